// Round 1
// 261.625 us; speedup vs baseline: 1.0427x; 1.0427x over previous
//
#include <hip/hip_runtime.h>

#define B_ 8
#define NH 12
#define NTOK 1025
#define FT 768
#define MROWS (B_*NTOK)      // 8200
#define QPAD 1025            // Q token stride (no pad needed)
#define CH2 34               // 32-token chunks
#define NQT 36               // 32-row Q tiles
#define NTT 34               // 32-token bias tiles
#define NRT18 18             // 64-row attn blocks
#define NDIST 3972
#define LOG2E 1.44269504089f

typedef __bf16 bf16x8 __attribute__((ext_vector_type(8)));
typedef __bf16 bf16x2 __attribute__((ext_vector_type(2)));
typedef float floatx4 __attribute__((ext_vector_type(4)));
typedef float floatx16 __attribute__((ext_vector_type(16)));
typedef int intx4 __attribute__((ext_vector_type(4)));

// async global->LDS, 16B/lane; LDS dst wave-uniform, HW scatters +lane*16.
__device__ __forceinline__ void async_ld16(const void* gp, void* lp) {
  __builtin_amdgcn_global_load_lds(
      (const __attribute__((address_space(1))) void*)gp,
      (__attribute__((address_space(3))) void*)lp, 16, 0, 0);
}

__global__ __launch_bounds__(256) void cvt_bf16(const float* __restrict__ src,
                                                __bf16* __restrict__ dst, int n4) {
  int i = blockIdx.x * 256 + threadIdx.x;
  if (i >= n4) return;
  float4 v = ((const float4*)src)[i];
  __bf16 o[4] = {(__bf16)v.x, (__bf16)v.y, (__bf16)v.z, (__bf16)v.w};
  *(uint2*)(dst + 4 * (size_t)i) = *(uint2*)o;
}

// table (NDIST, NH) fp32 -> tableT[h][dist] bf16, pre-scaled by log2(e).
__global__ __launch_bounds__(256) void table_prep(const float* __restrict__ table,
                                                  __bf16* __restrict__ tableT) {
  int i = blockIdx.x * 256 + threadIdx.x;
  if (i >= NH * NDIST) return;
  int h = i / NDIST, d = i - h * NDIST;
  tableT[i] = (__bf16)(table[(size_t)d * NH + h] * LOG2E);
}

// ---------------- relpos bias gather into 32x32 S^T C-fragment tiles ----------------
// idx block staged via coalesced loads into LDS (stride-33 pad -> conflict-free reads);
// gathers hit tableT[h][dist] bf16 (neighbor tokens -> +-1 entries -> L1 line reuse).
// Bb[h][qt][tt][lane*16+j]: bias[qrow=qt*32+(lane&31)][token=tt*32+(j&3)+8*(j>>2)+4*(lane>>5)]
// values pre-scaled by log2(e) (softmax uses exp2). pad tokens -> -1e30 mask.
__global__ __launch_bounds__(256) void bias_gather_t(
    const int* __restrict__ idx, const __bf16* __restrict__ tableT,
    __bf16* __restrict__ Bb) {
  __shared__ int ids_l[32][33];
  const int qt = blockIdx.x, tt = blockIdx.y;
  const int t = threadIdx.x;
  {
    const int row = t >> 3, c4 = (t & 7) * 4;
    int qrow = qt * 32 + row; if (qrow > NTOK - 1) qrow = NTOK - 1;
    const int* src = idx + (size_t)qrow * NTOK;
#pragma unroll
    for (int j = 0; j < 4; ++j) {
      int token = tt * 32 + c4 + j; if (token > NTOK - 1) token = NTOK - 1;
      ids_l[row][c4 + j] = src[token];
    }
  }
  __syncthreads();
  const int lane = t & 63, w = t >> 6;
  const int l31 = lane & 31, hb = lane >> 5;
  int ids[16]; bool ok[16];
#pragma unroll
  for (int j = 0; j < 16; ++j) {
    const int col = (j & 3) + 8 * (j >> 2) + 4 * hb;
    ok[j] = tt * 32 + col < NTOK;
    ids[j] = ids_l[l31][col];
  }
#pragma unroll
  for (int g = 0; g < 3; ++g) {
    const int h = w + g * 4;
    const __bf16* tb = tableT + (size_t)h * NDIST;
    __bf16 v[16] __attribute__((aligned(16)));
#pragma unroll
    for (int j = 0; j < 16; ++j)
      v[j] = ok[j] ? tb[ids[j]] : (__bf16)(-1e30f);
    uint4* dst = (uint4*)(Bb + (((size_t)h * NQT + qt) * NTT + tt) * 1024 + lane * 16);
    dst[0] = ((uint4*)v)[0];
    dst[1] = ((uint4*)v)[1];
  }
}

// ---------------- 128x128 GEMM core, lookahead-2 waitcnt pipeline ----------------
// 4 rotating LDS buffers; raw s_barrier + vmcnt(8): tiles k+1 AND k+2 stay in flight
// across the barrier (L2/L3 latency ~200-600cy now covered by 2 step-times).
// Hazard: write buf (k+2)&3 while readers last touched it at step k-2, which all
// waves completed before barrier(k-1) -> safe.
__device__ __forceinline__ void gemm128_pipe(
    const __bf16* __restrict__ A, const __bf16* __restrict__ W,
    int am0, int n0, int amax, __bf16* At, __bf16* Bt, floatx4 acc[4][4]) {
  const int tid = threadIdx.x, wave = tid >> 6, lane = tid & 63;
  const int l = lane & 15, qd = lane >> 4;
  const int wr = wave >> 1, wc = wave & 1;
  const int srow = lane >> 2, sg = lane & 3;
  const int r0 = wave * 32 + srow, r1 = r0 + 16;
  int gm0 = am0 + r0; if (gm0 > amax) gm0 = amax;
  int gm1 = am0 + r1; if (gm1 > amax) gm1 = amax;
  const int sw0 = (sg ^ (r0 & 3)) * 8;          // staging XOR swizzle (row&3)
  const __bf16* gA0 = A + (size_t)gm0 * FT + sw0;
  const __bf16* gA1 = A + (size_t)gm1 * FT + sw0;
  const __bf16* gB0 = W + (size_t)(n0 + r0) * FT + sw0;
  const __bf16* gB1 = W + (size_t)(n0 + r1) * FT + sw0;
  const int woff = wave * 32 * 32;
  const int fsw = (qd ^ (l & 3)) * 8;           // fragment-read swizzle

  auto issue = [&](int k, int buf) {
    __bf16* a = At + buf * 4096 + woff;
    __bf16* b = Bt + buf * 4096 + woff;
    async_ld16(gA0 + k * 32, a);
    async_ld16(gA1 + k * 32, a + 512);
    async_ld16(gB0 + k * 32, b);
    async_ld16(gB1 + k * 32, b + 512);
  };
  auto step = [&](int buf) {
    __builtin_amdgcn_s_barrier();
    const __bf16* ab = At + buf * 4096;
    const __bf16* bb = Bt + buf * 4096;
    bf16x8 aF[4], bF[4];
#pragma unroll
    for (int t = 0; t < 4; ++t)
      aF[t] = *(const bf16x8*)(ab + (wr * 64 + t * 16 + l) * 32 + fsw);
#pragma unroll
    for (int u = 0; u < 4; ++u)
      bF[u] = *(const bf16x8*)(bb + (wc * 64 + u * 16 + l) * 32 + fsw);
#pragma unroll
    for (int t = 0; t < 4; ++t)
#pragma unroll
      for (int u = 0; u < 4; ++u)
        acc[t][u] = __builtin_amdgcn_mfma_f32_16x16x32_bf16(aF[t], bF[u], acc[t][u], 0, 0, 0);
  };

  issue(0, 0);
  issue(1, 1);
  for (int k = 0; k < 24; ++k) {                // FT/32 = 24
    if (k + 2 < 24) {
      issue(k + 2, (k + 2) & 3);
      __builtin_amdgcn_s_waitcnt(0x0F78);       // vmcnt(8): k landed, k+1/k+2 in flight
    } else if (k + 1 < 24) {
      __builtin_amdgcn_s_waitcnt(0x0F74);       // vmcnt(4)
    } else {
      __builtin_amdgcn_s_waitcnt(0x0F70);       // vmcnt(0)
    }
    step(k & 3);
  }
}

// ---------------- QKV projection GEMM + bias/scale epilogue ----------------
// Per-batch M-tiling: 9 tiles of 128 per batch (72 m-tiles) -> no div-by-1025 anywhere,
// tok stays 4-aligned -> V epilogue is one aligned 8B store per (t,u); full tiles
// (ml<8) carry zero bounds checks. Grid swizzle: xcd = u&7, n fastest.
__global__ __launch_bounds__(256) void qkv_gemm128(
    const __bf16* __restrict__ tokens, const __bf16* __restrict__ qkvw,
    const float* __restrict__ qbias, const float* __restrict__ vbias,
    __bf16* __restrict__ Qb, __bf16* __restrict__ Kc, __bf16* __restrict__ Vc) {
  __shared__ __bf16 At[4 * 4096], Bt[4 * 4096];   // 64 KB
  const int u0 = blockIdx.x;
  const int c = u0 & 7, q0 = u0 >> 3;             // q0 in [0,162)
  const int mt = (q0 / 18) * 8 + c, ni = q0 % 18; // mt in [0,72)
  const int b = mt / 9, ml = mt - b * 9;
  const int am0 = b * NTOK + ml * 128, amax = b * NTOK + 1024;
  const int n0 = ni * 128;
  const int tid = threadIdx.x, wave = tid >> 6, lane = tid & 63;
  const int l = lane & 15, qd = lane >> 4;
  const int wr = wave >> 1, wc = wave & 1;
  floatx4 acc[4][4];
#pragma unroll
  for (int t = 0; t < 4; ++t)
#pragma unroll
    for (int u = 0; u < 4; ++u) acc[t][u] = (floatx4){0.f, 0.f, 0.f, 0.f};
  gemm128_pipe(tokens, qkvw, am0, n0, amax, At, Bt, acc);

  const int which = ni / 6;                       // 0=Q 1=K 2=V (block-uniform)
  const int nrem0 = (ni - which * 6) * 128;
  const bool full = (ml < 8);                     // edge tile: only tok==1024 valid
  const int tokb = ml * 128 + wr * 64 + qd * 4;

  if (which == 0) {
#pragma unroll
    for (int u = 0; u < 4; ++u) {
      const int rem = nrem0 + wc * 64 + u * 16 + l;
      const int h = rem >> 6, f = rem & 63;
      const size_t bhq = ((size_t)(b * NH + h)) * QPAD;
      const float qb = qbias[h * 64 + f];
#pragma unroll
      for (int t = 0; t < 4; ++t) {
        const int tok = tokb + t * 16;
        if (full) {
          __bf16* qp = Qb + (bhq + tok) * 64 + f;
#pragma unroll
          for (int r = 0; r < 4; ++r)
            qp[r * 64] = (__bf16)((acc[t][u][r] + qb) * (0.125f * LOG2E));
        } else {
#pragma unroll
          for (int r = 0; r < 4; ++r)
            if (tok + r < NTOK)
              Qb[(bhq + tok + r) * 64 + f] = (__bf16)((acc[t][u][r] + qb) * (0.125f * LOG2E));
        }
      }
    }
  } else if (which == 1) {
    // Kc 32-tok chunks: [bh][tok>>5][dg=f>>3][tok&31][f&7]
#pragma unroll
    for (int u = 0; u < 4; ++u) {
      const int rem = nrem0 + wc * 64 + u * 16 + l;
      const int f = rem & 63;
      const size_t bhc = ((size_t)(b * NH + (rem >> 6))) * CH2;
      const int dgo = (f >> 3) * 256 + (f & 7);
#pragma unroll
      for (int t = 0; t < 4; ++t) {
        const int tok = tokb + t * 16;
        if (full) {
          const size_t base = (bhc + (tok >> 5)) * 2048 + dgo + (tok & 31) * 8;
#pragma unroll
          for (int r = 0; r < 4; ++r) Kc[base + r * 8] = (__bf16)acc[t][u][r];
        } else {
#pragma unroll
          for (int r = 0; r < 4; ++r) {
            const int tk = tok + r;
            if (tk < NTOK)
              Kc[(bhc + (tk >> 5)) * 2048 + (f >> 3) * 256 + (tk & 31) * 8 + (f & 7)] =
                  (__bf16)acc[t][u][r];
          }
        }
      }
    }
  } else {
    // Vc 32-tok chunks: [bh][tok>>5][tg=(tok>>3)&3][f][tok&7]; tok 4-aligned ->
    // 4 consecutive outputs are one aligned 8B store.
#pragma unroll
    for (int u = 0; u < 4; ++u) {
      const int rem = nrem0 + wc * 64 + u * 16 + l;
      const int h = rem >> 6, f = rem & 63;
      const size_t bhc = ((size_t)(b * NH + h)) * CH2;
      const float vb = vbias[h * 64 + f];
#pragma unroll
      for (int t = 0; t < 4; ++t) {
        const int tok = tokb + t * 16;
        if (full) {
          __bf16 v4[4] __attribute__((aligned(8)));
#pragma unroll
          for (int r = 0; r < 4; ++r) v4[r] = (__bf16)(acc[t][u][r] + vb);
          const size_t e = (bhc + (tok >> 5)) * 2048 +
                           ((((tok >> 3) & 3) * 64 + f) << 3) + (tok & 7);
          *(uint2*)(Vc + e) = *(const uint2*)v4;
        } else {
#pragma unroll
          for (int r = 0; r < 4; ++r) {
            const int tk = tok + r;
            if (tk < NTOK)
              Vc[(bhc + (tk >> 5)) * 2048 + ((((tk >> 3) & 3) * 64 + f) << 3) + (tk & 7)] =
                  (__bf16)(acc[t][u][r] + vb);
          }
        }
      }
    }
  }
}

// ---------------- output projection GEMM + bias (fp32 out), per-batch tiling ----------------
__global__ __launch_bounds__(256) void proj_gemm128(
    const __bf16* __restrict__ Ao, const __bf16* __restrict__ projw,
    const float* __restrict__ projb, float* __restrict__ out) {
  __shared__ __bf16 At[4 * 4096], Bt[4 * 4096];
  const int u0 = blockIdx.x;
  const int c = u0 & 7, q0 = u0 >> 3;             // q0 in [0,54)
  const int mt = (q0 / 6) * 8 + c, ni = q0 % 6;   // mt in [0,72)
  const int b = mt / 9, ml = mt - b * 9;
  const int am0 = b * NTOK + ml * 128, amax = b * NTOK + 1024;
  const int n0 = ni * 128;
  const int tid = threadIdx.x, wave = tid >> 6, lane = tid & 63;
  const int l = lane & 15, qd = lane >> 4;
  const int wr = wave >> 1, wc = wave & 1;
  floatx4 acc[4][4];
#pragma unroll
  for (int t = 0; t < 4; ++t)
#pragma unroll
    for (int u = 0; u < 4; ++u) acc[t][u] = (floatx4){0.f, 0.f, 0.f, 0.f};
  gemm128_pipe(Ao, projw, am0, n0, amax, At, Bt, acc);

  const bool full = (ml < 8);
  const int tokb = ml * 128 + wr * 64 + qd * 4;
  const size_t rowb = (size_t)b * NTOK;
#pragma unroll
  for (int u = 0; u < 4; ++u) {
    const int gn = n0 + wc * 64 + u * 16 + l;
    const float pb = projb[gn];
#pragma unroll
    for (int t = 0; t < 4; ++t) {
      const int tok = tokb + t * 16;
      if (full) {
        float* op = out + (rowb + tok) * FT + gn;
#pragma unroll
        for (int r = 0; r < 4; ++r) op[(size_t)r * FT] = acc[t][u][r] + pb;
      } else {
#pragma unroll
        for (int r = 0; r < 4; ++r)
          if (tok + r < NTOK) out[(rowb + tok + r) * FT + gn] = acc[t][u][r] + pb;
      }
    }
  }
}

// ---------------- pipelined flash attention: 64 Q-rows / 2-wave block ----------------
// 32-token chunks; 4 rotating LDS buffer sets, lookahead-2 (wave0 stages K, wave1 V);
// bias prefetched 2 chunks deep so the bias register wait can't drain newer stage
// loads (vmcnt retires in order). vmcnt(10) = stage(c+1)4 + stage(c+2)4 + bias(c+2)2.
// S^T = K.Q^T (32x32x16); P = exp2(S + bias) [log2e pre-folded]; O^T = V^T.P^T.
// Pad tokens carry bias -1e30 -> exp2()==0, so un-zeroed K/V pad garbage is inert.
__global__ __launch_bounds__(128) void attn_flash(
    const __bf16* __restrict__ Qb, const __bf16* __restrict__ Kc,
    const __bf16* __restrict__ Vc, const __bf16* __restrict__ Bb,
    __bf16* __restrict__ Ao) {
  __shared__ __bf16 Kl[4][2048], Vl[4][2048];   // 32 KB total
  const int bh = blockIdx.x;
  const int rt = blockIdx.y;
  const int h = bh % NH, b = bh / NH;
  const int wave = threadIdx.x >> 6, lane = threadIdx.x & 63;
  const int l31 = lane & 31, hb = lane >> 5;
  const int qt = rt * 2 + wave;
  int qrow = qt * 32 + l31; if (qrow > NTOK - 1) qrow = NTOK - 1;

  // Q fragments (B-operand): B[n=qrow=lane&31][k = dk*16 + hb*8 + i]
  bf16x8 qf[4];
  {
    const __bf16* Qp = Qb + ((size_t)bh * QPAD + qrow) * 64 + hb * 8;
#pragma unroll
    for (int d = 0; d < 4; ++d) qf[d] = *(const bf16x8*)(Qp + d * 16);
  }

  floatx16 o0, o1;
#pragma unroll
  for (int j = 0; j < 16; ++j) { o0[j] = 0.f; o1[j] = 0.f; }
  float lsum = 0.f;

  const __bf16* KVg = (wave ? Vc : Kc) + (size_t)bh * CH2 * 2048;
  const __bf16* Bg = Bb + ((size_t)h * NQT + qt) * NTT * 1024 + lane * 16;

  auto issue = [&](int c, int buf) {
    const __bf16* src = KVg + (size_t)c * 2048 + lane * 8;
    __bf16* dst = wave ? Vl[buf] : Kl[buf];
#pragma unroll
    for (int ii = 0; ii < 4; ++ii) async_ld16(src + ii * 512, dst + ii * 512);
  };

  bf16x8 bc0 = *(const bf16x8*)(Bg);
  bf16x8 bc1 = *(const bf16x8*)(Bg + 8);
  bf16x8 b10 = *(const bf16x8*)(Bg + 1024);
  bf16x8 b11 = *(const bf16x8*)(Bg + 1024 + 8);
  issue(0, 0);
  issue(1, 1);
  for (int c = 0; c < CH2; ++c) {
    bf16x8 b20 = b10, b21 = b11;
    if (c + 2 < CH2) {
      b20 = *(const bf16x8*)(Bg + (size_t)(c + 2) * 1024);
      b21 = *(const bf16x8*)(Bg + (size_t)(c + 2) * 1024 + 8);
      issue(c + 2, (c + 2) & 3);
      __builtin_amdgcn_s_waitcnt(0x0F7A);   // vmcnt(10): chunk c landed, c+1/c+2 in flight
    } else if (c + 1 < CH2) {
      __builtin_amdgcn_s_waitcnt(0x0F74);   // vmcnt(4): only stage(c+1) still out
    } else {
      __builtin_amdgcn_s_waitcnt(0x0F70);   // vmcnt(0)
    }
    __builtin_amdgcn_s_barrier();
    const __bf16* Kb = Kl[c & 3];
    const __bf16* Vb = Vl[c & 3];

    // QK^T: S^T(32 tokens x 32 qrows)
    floatx16 st;
#pragma unroll
    for (int j = 0; j < 16; ++j) st[j] = 0.f;
#pragma unroll
    for (int dk = 0; dk < 4; ++dk) {
      bf16x8 a = *(const bf16x8*)(Kb + ((dk * 2 + hb) * 32 + l31) * 8);
      st = __builtin_amdgcn_mfma_f32_32x32x16_bf16(a, qf[dk], st, 0, 0, 0);
    }
    // P = exp2(S^T + bias'), accumulate l
    float e[16];
#pragma unroll
    for (int j = 0; j < 16; ++j) {
      const float bj = (float)(j < 8 ? bc0[j] : bc1[j - 8]);
      e[j] = __builtin_amdgcn_exp2f(st[j] + bj);
      lsum += e[j];
    }
    int pk[8];
#pragma unroll
    for (int j2 = 0; j2 < 8; ++j2) {
      bf16x2 pr = {(__bf16)e[2 * j2], (__bf16)e[2 * j2 + 1]};
      pk[j2] = __builtin_bit_cast(int, pr);
    }
    // PV: O^T += V^T . P^T (P^T B-frags via xor-32 exchange)
#pragma unroll
    for (int ks = 0; ks < 2; ++ks) {
      const int r01a = pk[4 * ks + 0], r01b = pk[4 * ks + 1];
      const int r23a = pk[4 * ks + 2], r23b = pk[4 * ks + 3];
      const int t01a = __shfl_xor(r01a, 32), t01b = __shfl_xor(r01b, 32);
      const int t23a = __shfl_xor(r23a, 32), t23b = __shfl_xor(r23b, 32);
      intx4 fi;
      fi[0] = hb ? t23a : r01a;
      fi[1] = hb ? t23b : r01b;
      fi[2] = hb ? r23a : t01a;
      fi[3] = hb ? r23b : t01b;
      bf16x8 pb = __builtin_bit_cast(bf16x8, fi);
      bf16x8 va0 = *(const bf16x8*)(Vb + ((ks * 2 + hb) * 64 + l31) * 8);
      bf16x8 va1 = *(const bf16x8*)(Vb + ((ks * 2 + hb) * 64 + 32 + l31) * 8);
      o0 = __builtin_amdgcn_mfma_f32_32x32x16_bf16(va0, pb, o0, 0, 0, 0);
      o1 = __builtin_amdgcn_mfma_f32_32x32x16_bf16(va1, pb, o1, 0, 0, 0);
    }
    bc0 = b10; bc1 = b11; b10 = b20; b11 = b21;
  }

  const float ltot = lsum + __shfl_xor(lsum, 32);
  const float rinv = 1.0f / ltot;
  const int tok = rt * 64 + wave * 32 + l31;
  if (tok < NTOK) {
    __bf16* op = Ao + ((size_t)b * NTOK + tok) * FT + h * 64;
#pragma unroll
    for (int ft = 0; ft < 2; ++ft) {
#pragma unroll
      for (int jg = 0; jg < 4; ++jg) {
        const int f = ft * 32 + jg * 8 + hb * 4;
        __bf16 v4[4] __attribute__((aligned(8)));
#pragma unroll
        for (int q = 0; q < 4; ++q) {
          const float ov = ft ? o1[jg * 4 + q] : o0[jg * 4 + q];
          v4[q] = (__bf16)(ov * rinv);
        }
        *(uint2*)(op + f) = *(uint2*)v4;
      }
    }
  }
}

extern "C" void kernel_launch(void* const* d_in, const int* in_sizes, int n_in,
                              void* d_out, int out_size, void* d_ws, size_t ws_size,
                              hipStream_t stream) {
  (void)in_sizes; (void)n_in; (void)out_size; (void)ws_size;
  const float* tokens = (const float*)d_in[0];
  const float* qkvw   = (const float*)d_in[1];
  const float* qbias  = (const float*)d_in[2];
  const float* vbias  = (const float*)d_in[3];
  const float* table  = (const float*)d_in[4];
  const float* projw  = (const float*)d_in[5];
  const float* projb  = (const float*)d_in[6];
  const int*   rpidx  = (const int*)d_in[7];
  float* out = (float*)d_out;
  char* ws = (char*)d_ws;

  const size_t QBQ = (size_t)B_ * NH * QPAD * 64 * 2;          // 12,595,200 B
  const size_t KVB = (size_t)B_ * NH * CH2 * 2048 * 2;         // 13,369,344 B
  const size_t BBT = (size_t)NH * NQT * NTT * 1024 * 2;        // 30,081,024 B
  const size_t AOB = (size_t)MROWS * FT * 2;                   // 12,595,200 B
  const size_t WQB = (size_t)3 * FT * FT * 2;
  const size_t WPB = (size_t)FT * FT * 2;
  __bf16* Qb = (__bf16*)(ws);
  __bf16* Kc = (__bf16*)(ws + QBQ);
  __bf16* Vc = (__bf16*)(ws + QBQ + KVB);
  __bf16* Bb = (__bf16*)(ws + QBQ + 2 * KVB);
  __bf16* Tb = (__bf16*)(ws + QBQ + 2 * KVB + BBT);  // tokens bf16; Ao aliases (dead after qkv)
  __bf16* Ao = Tb;
  __bf16* Wq = (__bf16*)(ws + QBQ + 2 * KVB + BBT + AOB);
  __bf16* Wp = (__bf16*)(ws + QBQ + 2 * KVB + BBT + AOB + WQB);
  __bf16* Tt = (__bf16*)(ws + QBQ + 2 * KVB + BBT + AOB + WQB + WPB);
  // total ~86.8 MB (below previous 87.5 MB)

  cvt_bf16<<<(MROWS * FT / 4 + 255) / 256, 256, 0, stream>>>(tokens, Tb, MROWS * FT / 4);
  cvt_bf16<<<(3 * FT * FT / 4 + 255) / 256, 256, 0, stream>>>(qkvw, Wq, 3 * FT * FT / 4);
  cvt_bf16<<<(FT * FT / 4 + 255) / 256, 256, 0, stream>>>(projw, Wp, FT * FT / 4);
  table_prep<<<(NH * NDIST + 255) / 256, 256, 0, stream>>>(table, Tt);
  bias_gather_t<<<dim3(NQT, NTT), 256, 0, stream>>>(rpidx, Tt, Bb);
  qkv_gemm128<<<8 * 9 * 18, 256, 0, stream>>>(Tb, Wq, qbias, vbias, Qb, Kc, Vc);
  attn_flash<<<dim3(B_ * NH, NRT18), 128, 0, stream>>>(Qb, Kc, Vc, Bb, Ao);
  proj_gemm128<<<8 * 9 * 6, 256, 0, stream>>>(Ao, Wp, projb, out);
}

// Round 2
// 245.676 us; speedup vs baseline: 1.1104x; 1.0649x over previous
//
#include <hip/hip_runtime.h>

#define B_ 8
#define NH 12
#define NTOK 1025
#define FT 768
#define MROWS (B_*NTOK)      // 8200
#define QPAD 1025            // Q token stride (no pad needed)
#define CH2 34               // 32-token chunks
#define NQT 36               // 32-row Q tiles
#define NTT 34               // 32-token bias tiles
#define NDIST 3972
#define LOG2E 1.44269504089f

typedef __bf16 bf16x8 __attribute__((ext_vector_type(8)));
typedef __bf16 bf16x2 __attribute__((ext_vector_type(2)));
typedef float floatx4 __attribute__((ext_vector_type(4)));
typedef float floatx16 __attribute__((ext_vector_type(16)));
typedef int intx4 __attribute__((ext_vector_type(4)));

// async global->LDS, 16B/lane; LDS dst wave-uniform, HW scatters +lane*16.
__device__ __forceinline__ void async_ld16(const void* gp, void* lp) {
  __builtin_amdgcn_global_load_lds(
      (const __attribute__((address_space(1))) void*)gp,
      (__attribute__((address_space(3))) void*)lp, 16, 0, 0);
}

__global__ __launch_bounds__(256) void cvt_bf16(const float* __restrict__ src,
                                                __bf16* __restrict__ dst, int n4) {
  int i = blockIdx.x * 256 + threadIdx.x;
  if (i >= n4) return;
  float4 v = ((const float4*)src)[i];
  __bf16 o[4] = {(__bf16)v.x, (__bf16)v.y, (__bf16)v.z, (__bf16)v.w};
  *(uint2*)(dst + 4 * (size_t)i) = *(uint2*)o;
}

// table (NDIST, NH) fp32 -> tableT[h][dist] bf16, pre-scaled by log2(e).
__global__ __launch_bounds__(256) void table_prep(const float* __restrict__ table,
                                                  __bf16* __restrict__ tableT) {
  int i = blockIdx.x * 256 + threadIdx.x;
  if (i >= NH * NDIST) return;
  int h = i / NDIST, d = i - h * NDIST;
  tableT[i] = (__bf16)(table[(size_t)d * NH + h] * LOG2E);
}

// ---------------- relpos bias gather into 32x32 S^T C-fragment tiles ----------------
// idx block staged via coalesced loads into LDS; gathers hit tableT[h][dist] bf16.
// Bb[h][qt][tt][lane*16+j]: bias[qrow=qt*32+(lane&31)][token=tt*32+(j&3)+8*(j>>2)+4*(lane>>5)]
// values pre-scaled by log2(e) (softmax uses exp2). pad tokens -> -1e30 mask.
__global__ __launch_bounds__(256) void bias_gather_t(
    const int* __restrict__ idx, const __bf16* __restrict__ tableT,
    __bf16* __restrict__ Bb) {
  __shared__ int ids_l[32][33];
  const int qt = blockIdx.x, tt = blockIdx.y;
  const int t = threadIdx.x;
  {
    const int row = t >> 3, c4 = (t & 7) * 4;
    int qrow = qt * 32 + row; if (qrow > NTOK - 1) qrow = NTOK - 1;
    const int* src = idx + (size_t)qrow * NTOK;
#pragma unroll
    for (int j = 0; j < 4; ++j) {
      int token = tt * 32 + c4 + j; if (token > NTOK - 1) token = NTOK - 1;
      ids_l[row][c4 + j] = src[token];
    }
  }
  __syncthreads();
  const int lane = t & 63, w = t >> 6;
  const int l31 = lane & 31, hb = lane >> 5;
  int ids[16]; bool ok[16];
#pragma unroll
  for (int j = 0; j < 16; ++j) {
    const int col = (j & 3) + 8 * (j >> 2) + 4 * hb;
    ok[j] = tt * 32 + col < NTOK;
    ids[j] = ids_l[l31][col];
  }
#pragma unroll
  for (int g = 0; g < 3; ++g) {
    const int h = w + g * 4;
    const __bf16* tb = tableT + (size_t)h * NDIST;
    __bf16 v[16] __attribute__((aligned(16)));
#pragma unroll
    for (int j = 0; j < 16; ++j)
      v[j] = ok[j] ? tb[ids[j]] : (__bf16)(-1e30f);
    uint4* dst = (uint4*)(Bb + (((size_t)h * NQT + qt) * NTT + tt) * 1024 + lane * 16);
    dst[0] = ((uint4*)v)[0];
    dst[1] = ((uint4*)v)[1];
  }
}

// ---------------- 128x128 GEMM core, lookahead-3 waitcnt pipeline ----------------
// 5 rotating LDS buffers; raw s_barrier + vmcnt(12): tiles k+1..k+3 stay in flight
// across the barrier (~540cy of cover vs ~600cy L3 latency).
// Hazard: writing buf (k+3)%5 while readers last touched it at step k-2, which all
// waves completed before barrier(k-1) -> safe.
__device__ __forceinline__ void gemm128_pipe(
    const __bf16* __restrict__ A, const __bf16* __restrict__ W,
    int am0, int n0, int amax, __bf16* At, __bf16* Bt, floatx4 acc[4][4]) {
  const int tid = threadIdx.x, wave = tid >> 6, lane = tid & 63;
  const int l = lane & 15, qd = lane >> 4;
  const int wr = wave >> 1, wc = wave & 1;
  const int srow = lane >> 2, sg = lane & 3;
  const int r0 = wave * 32 + srow, r1 = r0 + 16;
  int gm0 = am0 + r0; if (gm0 > amax) gm0 = amax;
  int gm1 = am0 + r1; if (gm1 > amax) gm1 = amax;
  const int sw0 = (sg ^ (r0 & 3)) * 8;          // staging XOR swizzle (row&3)
  const __bf16* gA0 = A + (size_t)gm0 * FT + sw0;
  const __bf16* gA1 = A + (size_t)gm1 * FT + sw0;
  const __bf16* gB0 = W + (size_t)(n0 + r0) * FT + sw0;
  const __bf16* gB1 = W + (size_t)(n0 + r1) * FT + sw0;
  const int woff = wave * 32 * 32;
  const int fsw = (qd ^ (l & 3)) * 8;           // fragment-read swizzle

  auto issue = [&](int k, int buf) {
    __bf16* a = At + buf * 4096 + woff;
    __bf16* b = Bt + buf * 4096 + woff;
    async_ld16(gA0 + k * 32, a);
    async_ld16(gA1 + k * 32, a + 512);
    async_ld16(gB0 + k * 32, b);
    async_ld16(gB1 + k * 32, b + 512);
  };
  auto step = [&](int buf) {
    __builtin_amdgcn_s_barrier();
    const __bf16* ab = At + buf * 4096;
    const __bf16* bb = Bt + buf * 4096;
    bf16x8 aF[4], bF[4];
#pragma unroll
    for (int t = 0; t < 4; ++t)
      aF[t] = *(const bf16x8*)(ab + (wr * 64 + t * 16 + l) * 32 + fsw);
#pragma unroll
    for (int u = 0; u < 4; ++u)
      bF[u] = *(const bf16x8*)(bb + (wc * 64 + u * 16 + l) * 32 + fsw);
#pragma unroll
    for (int t = 0; t < 4; ++t)
#pragma unroll
      for (int u = 0; u < 4; ++u)
        acc[t][u] = __builtin_amdgcn_mfma_f32_16x16x32_bf16(aF[t], bF[u], acc[t][u], 0, 0, 0);
  };

  issue(0, 0);
  issue(1, 1);
  issue(2, 2);
  int b0 = 0, b3 = 3;
  for (int k = 0; k < 24; ++k) {                // FT/32 = 24
    if (k < 21) {
      issue(k + 3, b3);
      __builtin_amdgcn_s_waitcnt(0x0F7C);       // vmcnt(12): k landed, k+1..k+3 in flight
    } else if (k == 21) {
      __builtin_amdgcn_s_waitcnt(0x0F78);       // vmcnt(8)
    } else if (k == 22) {
      __builtin_amdgcn_s_waitcnt(0x0F74);       // vmcnt(4)
    } else {
      __builtin_amdgcn_s_waitcnt(0x0F70);       // vmcnt(0)
    }
    step(b0);
    ++b0; if (b0 == 5) b0 = 0;
    ++b3; if (b3 == 5) b3 = 0;
  }
}

// ---------------- QKV projection GEMM + bias/scale epilogue ----------------
// Per-batch M-tiling: 9 tiles of 128 per batch (72 m-tiles) -> no div-by-1025 anywhere,
// tok stays 4-aligned -> V epilogue is one aligned 8B store per (t,u); full tiles
// (ml<8) carry zero bounds checks. Grid swizzle: xcd = u&7, n fastest.
__global__ __launch_bounds__(256) void qkv_gemm128(
    const __bf16* __restrict__ tokens, const __bf16* __restrict__ qkvw,
    const float* __restrict__ qbias, const float* __restrict__ vbias,
    __bf16* __restrict__ Qb, __bf16* __restrict__ Kc, __bf16* __restrict__ Vc) {
  __shared__ __bf16 At[5 * 4096], Bt[5 * 4096];   // 80 KB -> 2 blocks/CU
  const int u0 = blockIdx.x;
  const int c = u0 & 7, q0 = u0 >> 3;             // q0 in [0,162)
  const int mt = (q0 / 18) * 8 + c, ni = q0 % 18; // mt in [0,72)
  const int b = mt / 9, ml = mt - b * 9;
  const int am0 = b * NTOK + ml * 128, amax = b * NTOK + 1024;
  const int n0 = ni * 128;
  const int tid = threadIdx.x, wave = tid >> 6, lane = tid & 63;
  const int l = lane & 15, qd = lane >> 4;
  const int wr = wave >> 1, wc = wave & 1;
  floatx4 acc[4][4];
#pragma unroll
  for (int t = 0; t < 4; ++t)
#pragma unroll
    for (int u = 0; u < 4; ++u) acc[t][u] = (floatx4){0.f, 0.f, 0.f, 0.f};
  gemm128_pipe(tokens, qkvw, am0, n0, amax, At, Bt, acc);

  const int which = ni / 6;                       // 0=Q 1=K 2=V (block-uniform)
  const int nrem0 = (ni - which * 6) * 128;
  const bool full = (ml < 8);                     // edge tile: only tok==1024 valid
  const int tokb = ml * 128 + wr * 64 + qd * 4;

  if (which == 0) {
#pragma unroll
    for (int u = 0; u < 4; ++u) {
      const int rem = nrem0 + wc * 64 + u * 16 + l;
      const int h = rem >> 6, f = rem & 63;
      const size_t bhq = ((size_t)(b * NH + h)) * QPAD;
      const float qb = qbias[h * 64 + f];
#pragma unroll
      for (int t = 0; t < 4; ++t) {
        const int tok = tokb + t * 16;
        if (full) {
          __bf16* qp = Qb + (bhq + tok) * 64 + f;
#pragma unroll
          for (int r = 0; r < 4; ++r)
            qp[r * 64] = (__bf16)((acc[t][u][r] + qb) * (0.125f * LOG2E));
        } else {
#pragma unroll
          for (int r = 0; r < 4; ++r)
            if (tok + r < NTOK)
              Qb[(bhq + tok + r) * 64 + f] = (__bf16)((acc[t][u][r] + qb) * (0.125f * LOG2E));
        }
      }
    }
  } else if (which == 1) {
    // Kc 32-tok chunks: [bh][tok>>5][dg=f>>3][tok&31][f&7]
#pragma unroll
    for (int u = 0; u < 4; ++u) {
      const int rem = nrem0 + wc * 64 + u * 16 + l;
      const int f = rem & 63;
      const size_t bhc = ((size_t)(b * NH + (rem >> 6))) * CH2;
      const int dgo = (f >> 3) * 256 + (f & 7);
#pragma unroll
      for (int t = 0; t < 4; ++t) {
        const int tok = tokb + t * 16;
        if (full) {
          const size_t base = (bhc + (tok >> 5)) * 2048 + dgo + (tok & 31) * 8;
#pragma unroll
          for (int r = 0; r < 4; ++r) Kc[base + r * 8] = (__bf16)acc[t][u][r];
        } else {
#pragma unroll
          for (int r = 0; r < 4; ++r) {
            const int tk = tok + r;
            if (tk < NTOK)
              Kc[(bhc + (tk >> 5)) * 2048 + (f >> 3) * 256 + (tk & 31) * 8 + (f & 7)] =
                  (__bf16)acc[t][u][r];
          }
        }
      }
    }
  } else {
    // Vc 32-tok chunks: [bh][tok>>5][tg=(tok>>3)&3][f][tok&7]; tok 4-aligned ->
    // 4 consecutive outputs are one aligned 8B store.
#pragma unroll
    for (int u = 0; u < 4; ++u) {
      const int rem = nrem0 + wc * 64 + u * 16 + l;
      const int h = rem >> 6, f = rem & 63;
      const size_t bhc = ((size_t)(b * NH + h)) * CH2;
      const float vb = vbias[h * 64 + f];
#pragma unroll
      for (int t = 0; t < 4; ++t) {
        const int tok = tokb + t * 16;
        if (full) {
          __bf16 v4[4] __attribute__((aligned(8)));
#pragma unroll
          for (int r = 0; r < 4; ++r) v4[r] = (__bf16)(acc[t][u][r] + vb);
          const size_t e = (bhc + (tok >> 5)) * 2048 +
                           ((((tok >> 3) & 3) * 64 + f) << 3) + (tok & 7);
          *(uint2*)(Vc + e) = *(const uint2*)v4;
        } else {
#pragma unroll
          for (int r = 0; r < 4; ++r) {
            const int tk = tok + r;
            if (tk < NTOK)
              Vc[(bhc + (tk >> 5)) * 2048 + ((((tk >> 3) & 3) * 64 + f) << 3) + (tk & 7)] =
                  (__bf16)(acc[t][u][r] + vb);
          }
        }
      }
    }
  }
}

// ---------------- output projection GEMM + bias (fp32 out), per-batch tiling ----------------
__global__ __launch_bounds__(256) void proj_gemm128(
    const __bf16* __restrict__ Ao, const __bf16* __restrict__ projw,
    const float* __restrict__ projb, float* __restrict__ out) {
  __shared__ __bf16 At[5 * 4096], Bt[5 * 4096];
  const int u0 = blockIdx.x;
  const int c = u0 & 7, q0 = u0 >> 3;             // q0 in [0,54)
  const int mt = (q0 / 6) * 8 + c, ni = q0 % 6;   // mt in [0,72)
  const int b = mt / 9, ml = mt - b * 9;
  const int am0 = b * NTOK + ml * 128, amax = b * NTOK + 1024;
  const int n0 = ni * 128;
  const int tid = threadIdx.x, wave = tid >> 6, lane = tid & 63;
  const int l = lane & 15, qd = lane >> 4;
  const int wr = wave >> 1, wc = wave & 1;
  floatx4 acc[4][4];
#pragma unroll
  for (int t = 0; t < 4; ++t)
#pragma unroll
    for (int u = 0; u < 4; ++u) acc[t][u] = (floatx4){0.f, 0.f, 0.f, 0.f};
  gemm128_pipe(Ao, projw, am0, n0, amax, At, Bt, acc);

  const bool full = (ml < 8);
  const int tokb = ml * 128 + wr * 64 + qd * 4;
  const size_t rowb = (size_t)b * NTOK;
#pragma unroll
  for (int u = 0; u < 4; ++u) {
    const int gn = n0 + wc * 64 + u * 16 + l;
    const float pb = projb[gn];
#pragma unroll
    for (int t = 0; t < 4; ++t) {
      const int tok = tokb + t * 16;
      if (full) {
        float* op = out + (rowb + tok) * FT + gn;
#pragma unroll
        for (int r = 0; r < 4; ++r) op[(size_t)r * FT] = acc[t][u][r] + pb;
      } else {
#pragma unroll
        for (int r = 0; r < 4; ++r)
          if (tok + r < NTOK) out[(rowb + tok + r) * FT + gn] = acc[t][u][r] + pb;
      }
    }
  }
}

// ---------------- pipelined flash attention: 4 waves / block, shared K/V staging ----------------
// Each wave owns one 32-row Q tile (qt = blockIdx.y*4 + wave); all 4 waves share the
// same bh's K/V chunks. Staging split: waves 0,1 stage K halves; 2,3 stage V halves
// (2KB each). 5 rotating LDS buffer sets (40KB -> 4 blocks/CU = 16 waves/CU), stage
// lookahead ~2.5 chunks; bias double-buffered in regs (loaded c+2 after compute c).
// Per-iter queue (per wave): [s(c),b(c),s(c+1),b(c+1),s(c+2)] -> steady wait vmcnt(6)
// before the barrier publishes all 4 waves' stages. Buf hazard: (c+3)%5 last read at
// compute(c-2), finished by all waves before barrier(c-1) -> safe.
// S^T = K.Q^T (32x32x16); P = exp2(S + bias) [log2e pre-folded]; O^T = V^T.P^T.
// Pad tokens carry bias -1e30 -> exp2()==0, so un-zeroed K/V pad garbage is inert.
__global__ __launch_bounds__(256) void attn_flash(
    const __bf16* __restrict__ Qb, const __bf16* __restrict__ Kc,
    const __bf16* __restrict__ Vc, const __bf16* __restrict__ Bb,
    __bf16* __restrict__ Ao) {
  __shared__ __bf16 Kl[5][2048], Vl[5][2048];   // 40 KB total
  const int bh = blockIdx.x;
  const int h = bh % NH, b = bh / NH;
  const int wave = threadIdx.x >> 6, lane = threadIdx.x & 63;
  const int l31 = lane & 31, hb = lane >> 5;
  const int qt = blockIdx.y * 4 + wave;
  int qrow = qt * 32 + l31; if (qrow > NTOK - 1) qrow = NTOK - 1;

  // Q fragments (B-operand): B[n=qrow=lane&31][k = dk*16 + hb*8 + i]
  bf16x8 qf[4];
  {
    const __bf16* Qp = Qb + ((size_t)bh * QPAD + qrow) * 64 + hb * 8;
#pragma unroll
    for (int d = 0; d < 4; ++d) qf[d] = *(const bf16x8*)(Qp + d * 16);
  }

  floatx16 o0, o1;
#pragma unroll
  for (int j = 0; j < 16; ++j) { o0[j] = 0.f; o1[j] = 0.f; }
  float lsum = 0.f;

  // staging role: waves 0,1 -> K halves; waves 2,3 -> V halves (1KB x2 each)
  const int sw = wave & 1;
  const __bf16* Sg = ((wave < 2) ? Kc : Vc) + (size_t)bh * CH2 * 2048 +
                     sw * 1024 + lane * 8;
  __bf16* Sl0 = ((wave < 2) ? &Kl[0][0] : &Vl[0][0]) + sw * 1024;
  const __bf16* Bg = Bb + ((size_t)h * NQT + qt) * NTT * 1024 + lane * 16;

  auto issueS = [&](int c, int buf) {
    const __bf16* src = Sg + (size_t)c * 2048;
    __bf16* dst = Sl0 + buf * 2048;
    async_ld16(src, dst);
    async_ld16(src + 512, dst + 512);
  };

  auto compute = [&](int buf, bf16x8 cb0, bf16x8 cb1) {
    const __bf16* Kb = &Kl[buf][0];
    const __bf16* Vb = &Vl[buf][0];
    // QK^T: S^T(32 tokens x 32 qrows)
    floatx16 st;
#pragma unroll
    for (int j = 0; j < 16; ++j) st[j] = 0.f;
#pragma unroll
    for (int dk = 0; dk < 4; ++dk) {
      bf16x8 a = *(const bf16x8*)(Kb + ((dk * 2 + hb) * 32 + l31) * 8);
      st = __builtin_amdgcn_mfma_f32_32x32x16_bf16(a, qf[dk], st, 0, 0, 0);
    }
    // P = exp2(S^T + bias'), accumulate l
    float e[16];
#pragma unroll
    for (int j = 0; j < 16; ++j) {
      const float bj = (float)(j < 8 ? cb0[j] : cb1[j - 8]);
      e[j] = __builtin_amdgcn_exp2f(st[j] + bj);
      lsum += e[j];
    }
    int pk[8];
#pragma unroll
    for (int j2 = 0; j2 < 8; ++j2) {
      bf16x2 pr = {(__bf16)e[2 * j2], (__bf16)e[2 * j2 + 1]};
      pk[j2] = __builtin_bit_cast(int, pr);
    }
    // PV: O^T += V^T . P^T (P^T B-frags via xor-32 exchange)
#pragma unroll
    for (int ks = 0; ks < 2; ++ks) {
      const int r01a = pk[4 * ks + 0], r01b = pk[4 * ks + 1];
      const int r23a = pk[4 * ks + 2], r23b = pk[4 * ks + 3];
      const int t01a = __shfl_xor(r01a, 32), t01b = __shfl_xor(r01b, 32);
      const int t23a = __shfl_xor(r23a, 32), t23b = __shfl_xor(r23b, 32);
      intx4 fi;
      fi[0] = hb ? t23a : r01a;
      fi[1] = hb ? t23b : r01b;
      fi[2] = hb ? r23a : t01a;
      fi[3] = hb ? r23b : t01b;
      bf16x8 pb = __builtin_bit_cast(bf16x8, fi);
      bf16x8 va0 = *(const bf16x8*)(Vb + ((ks * 2 + hb) * 64 + l31) * 8);
      bf16x8 va1 = *(const bf16x8*)(Vb + ((ks * 2 + hb) * 64 + 32 + l31) * 8);
      o0 = __builtin_amdgcn_mfma_f32_32x32x16_bf16(va0, pb, o0, 0, 0, 0);
      o1 = __builtin_amdgcn_mfma_f32_32x32x16_bf16(va1, pb, o1, 0, 0, 0);
    }
  };

  // prologue: queue order [qf(4)] s0,b0,s1,b1,s2  (qf retires with first wait)
  issueS(0, 0);
  bf16x8 bA0 = *(const bf16x8*)(Bg);
  bf16x8 bA1 = *(const bf16x8*)(Bg + 8);
  issueS(1, 1);
  bf16x8 bB0 = *(const bf16x8*)(Bg + 1024);
  bf16x8 bB1 = *(const bf16x8*)(Bg + 1024 + 8);
  issueS(2, 2);

  int bc = 0;                                    // buf index for even c
  for (int ci = 0; ci < 15; ++ci) {
    const int c = 2 * ci;
    // even iter (parity A)
    __builtin_amdgcn_s_waitcnt(0x0F76);          // vmcnt(6): s(c),b(c) landed
    __builtin_amdgcn_s_barrier();
    compute(bc, bA0, bA1);
    bA0 = *(const bf16x8*)(Bg + (size_t)(c + 2) * 1024);
    bA1 = *(const bf16x8*)(Bg + (size_t)(c + 2) * 1024 + 8);
    { int b3 = bc + 3; if (b3 >= 5) b3 -= 5; issueS(c + 3, b3); }
    // odd iter (parity B)
    int bc1 = bc + 1; if (bc1 == 5) bc1 = 0;
    __builtin_amdgcn_s_waitcnt(0x0F76);          // vmcnt(6)
    __builtin_amdgcn_s_barrier();
    compute(bc1, bB0, bB1);
    bB0 = *(const bf16x8*)(Bg + (size_t)(c + 3) * 1024);
    bB1 = *(const bf16x8*)(Bg + (size_t)(c + 3) * 1024 + 8);
    { int b4 = bc + 4; if (b4 >= 5) b4 -= 5; issueS(c + 4, b4); }
    bc += 2; if (bc >= 5) bc -= 5;
  }
  // c=30 (A): bc==0 here (30%5)
  __builtin_amdgcn_s_waitcnt(0x0F76);            // vmcnt(6)
  __builtin_amdgcn_s_barrier();
  compute(0, bA0, bA1);
  bA0 = *(const bf16x8*)(Bg + (size_t)32 * 1024);
  bA1 = *(const bf16x8*)(Bg + (size_t)32 * 1024 + 8);
  issueS(33, 3);                                 // 33 % 5
  // c=31 (B)
  __builtin_amdgcn_s_waitcnt(0x0F76);            // vmcnt(6)
  __builtin_amdgcn_s_barrier();
  compute(1, bB0, bB1);
  bB0 = *(const bf16x8*)(Bg + (size_t)33 * 1024);
  bB1 = *(const bf16x8*)(Bg + (size_t)33 * 1024 + 8);
  // c=32 (A): queue [s32,b32,s33,b33] -> wait vmcnt(4)
  __builtin_amdgcn_s_waitcnt(0x0F74);
  __builtin_amdgcn_s_barrier();
  compute(2, bA0, bA1);
  // c=33 (B)
  __builtin_amdgcn_s_waitcnt(0x0F70);
  __builtin_amdgcn_s_barrier();
  compute(3, bB0, bB1);

  const float ltot = lsum + __shfl_xor(lsum, 32);
  const float rinv = 1.0f / ltot;
  const int tok = qt * 32 + l31;
  if (tok < NTOK) {
    __bf16* op = Ao + ((size_t)b * NTOK + tok) * FT + h * 64;
#pragma unroll
    for (int ft = 0; ft < 2; ++ft) {
#pragma unroll
      for (int jg = 0; jg < 4; ++jg) {
        const int f = ft * 32 + jg * 8 + hb * 4;
        __bf16 v4[4] __attribute__((aligned(8)));
#pragma unroll
        for (int q = 0; q < 4; ++q) {
          const float ov = ft ? o1[jg * 4 + q] : o0[jg * 4 + q];
          v4[q] = (__bf16)(ov * rinv);
        }
        *(uint2*)(op + f) = *(uint2*)v4;
      }
    }
  }
}

extern "C" void kernel_launch(void* const* d_in, const int* in_sizes, int n_in,
                              void* d_out, int out_size, void* d_ws, size_t ws_size,
                              hipStream_t stream) {
  (void)in_sizes; (void)n_in; (void)out_size; (void)ws_size;
  const float* tokens = (const float*)d_in[0];
  const float* qkvw   = (const float*)d_in[1];
  const float* qbias  = (const float*)d_in[2];
  const float* vbias  = (const float*)d_in[3];
  const float* table  = (const float*)d_in[4];
  const float* projw  = (const float*)d_in[5];
  const float* projb  = (const float*)d_in[6];
  const int*   rpidx  = (const int*)d_in[7];
  float* out = (float*)d_out;
  char* ws = (char*)d_ws;

  const size_t QBQ = (size_t)B_ * NH * QPAD * 64 * 2;          // 12,595,200 B
  const size_t KVB = (size_t)B_ * NH * CH2 * 2048 * 2;         // 13,369,344 B
  const size_t BBT = (size_t)NH * NQT * NTT * 1024 * 2;        // 30,081,024 B
  const size_t AOB = (size_t)MROWS * FT * 2;                   // 12,595,200 B
  const size_t WQB = (size_t)3 * FT * FT * 2;
  const size_t WPB = (size_t)FT * FT * 2;
  __bf16* Qb = (__bf16*)(ws);
  __bf16* Kc = (__bf16*)(ws + QBQ);
  __bf16* Vc = (__bf16*)(ws + QBQ + KVB);
  __bf16* Bb = (__bf16*)(ws + QBQ + 2 * KVB);
  __bf16* Tb = (__bf16*)(ws + QBQ + 2 * KVB + BBT);  // tokens bf16; Ao aliases (dead after qkv)
  __bf16* Ao = Tb;
  __bf16* Wq = (__bf16*)(ws + QBQ + 2 * KVB + BBT + AOB);
  __bf16* Wp = (__bf16*)(ws + QBQ + 2 * KVB + BBT + AOB + WQB);
  __bf16* Tt = (__bf16*)(ws + QBQ + 2 * KVB + BBT + AOB + WQB + WPB);
  // total ~86.8 MB

  cvt_bf16<<<(MROWS * FT / 4 + 255) / 256, 256, 0, stream>>>(tokens, Tb, MROWS * FT / 4);
  cvt_bf16<<<(3 * FT * FT / 4 + 255) / 256, 256, 0, stream>>>(qkvw, Wq, 3 * FT * FT / 4);
  cvt_bf16<<<(FT * FT / 4 + 255) / 256, 256, 0, stream>>>(projw, Wp, FT * FT / 4);
  table_prep<<<(NH * NDIST + 255) / 256, 256, 0, stream>>>(table, Tt);
  bias_gather_t<<<dim3(NQT, NTT), 256, 0, stream>>>(rpidx, Tt, Bb);
  qkv_gemm128<<<8 * 9 * 18, 256, 0, stream>>>(Tb, Wq, qbias, vbias, Qb, Kc, Vc);
  attn_flash<<<dim3(B_ * NH, 9), 256, 0, stream>>>(Qb, Kc, Vc, Bb, Ao);
  proj_gemm128<<<8 * 9 * 6, 256, 0, stream>>>(Ao, Wp, projb, out);
}